// Round 13
// baseline (453.683 us; speedup 1.0000x reference)
//
#include <hip/hip_runtime.h>

#define NCELL 24576      // 128*192 feature cells
#define NTOT  221184     // NCELL * 9
#define NBIN13 8192      // 13-bit score-key histogram bins (LDS)
#define TOPN  6000
#define POSTN 300
#define NPADR 6016       // padded candidate count (94 words of 64)
#define NW    94         // suppression-mask words per row
#define CW    8          // words per scan chunk (512 ranks)
#define NCHUNK 12        // ceil(94/8)
#define NCB   16         // front blocks
#define SLOT  1024       // cbuf slot per front block
#define CAP2  (NCB*SLOT) // 16384 total cbuf slots
#define MAGIC1 0x13572468u
#define MAGIC2 0x2468ACE1u

// ---------------- fused front: decode -> (16-blk barrier) -> hist/T/compact ->
// ---------------- (16-blk barrier) -> rank+scatter ----------------
__global__ __launch_bounds__(1024) void front_kernel(const float* __restrict__ scores,
                                                     const float* __restrict__ deltas,
                                                     const float* __restrict__ iminfo,
                                                     float4* __restrict__ boxes,
                                                     unsigned* __restrict__ skeys,
                                                     unsigned* __restrict__ flags,  // [0..15]=b1 [16..31]=b2 [32..47]=cnts
                                                     unsigned long long* __restrict__ cbuf,
                                                     float4* __restrict__ sortedbox) {
#pragma clang fp contract(off)
    __shared__ unsigned hist[NBIN13];      // 32 KB
    __shared__ unsigned psum[1024];
    __shared__ unsigned csum[256];
    __shared__ unsigned long long jk[512]; // rank phase j-tile
    __shared__ unsigned scnt[NCB];
    __shared__ unsigned sB, sAbove, sT, sCount;
    int tid = threadIdx.x, bid = blockIdx.x;

    // ---- phase A: decode own cell slice (1536 cells) ----
    {
        const float AW[9] = {184.f,368.f,736.f,128.f,256.f,512.f, 88.f,176.f,352.f};
        const float AH[9] = { 96.f,192.f,384.f,128.f,256.f,512.f,176.f,352.f,704.f};
        float imh = iminfo[0], imw = iminfo[1], ims = iminfo[2];
        float xhi = imw - 1.0f, yhi = imh - 1.0f;
        float ms = 16.0f * ims;
        for (int cc = tid; cc < NCELL / NCB; cc += 1024) {
            int c = bid * (NCELL / NCB) + cc;
            float sx = (float)((c >> 7) << 4);   // (c/128)*16  -- 'ij' meshgrid quirk
            float sy = (float)((c & 127) << 4);  // (c%128)*16
            float ctrx = sx + 8.0f, ctry = sy + 8.0f;
            const float* sbase = scores + 9 * NCELL + c;
            const float* dbase = deltas + c;
#pragma unroll
            for (int a = 0; a < 9; ++a) {
                float sc = sbase[a * NCELL];
                float dx = dbase[(4 * a + 0) * NCELL];
                float dy = dbase[(4 * a + 1) * NCELL];
                float dw = dbase[(4 * a + 2) * NCELL];
                float dh = dbase[(4 * a + 3) * NCELL];
                float pcx = dx * AW[a] + ctrx;
                float pcy = dy * AH[a] + ctry;
                float pw = expf(dw) * AW[a];
                float ph = expf(dh) * AH[a];
                float x1 = pcx - 0.5f * pw;
                float y1 = pcy - 0.5f * ph;
                float x2 = pcx + 0.5f * pw;
                float y2 = pcy + 0.5f * ph;
                x1 = fminf(fmaxf(x1, 0.0f), xhi);
                x2 = fminf(fmaxf(x2, 0.0f), xhi);
                y1 = fminf(fmaxf(y1, 0.0f), yhi);
                y2 = fminf(fmaxf(y2, 0.0f), yhi);
                bool valid = ((x2 - x1 + 1.0f) >= ms) && ((y2 - y1 + 1.0f) >= ms);
                unsigned u = __float_as_uint(sc);
                unsigned key = (u & 0x80000000u) ? ~u : (u | 0x80000000u);
                if (!valid) key = 0x007FFFFFu;   // sort key of -inf
                boxes[a * NCELL + c] = make_float4(x1, y1, x2, y2);
                skeys[a * NCELL + c] = key;
            }
        }
    }
    // init hist while waiting is not allowed before barrier (we need it after) -- do now, it's local
    for (int b = tid; b < NBIN13; b += 1024) hist[b] = 0u;
    if (tid == 0) sCount = 0u;
    // ---- 16-block barrier #1 (agent scope; 16 fences total) ----
    __syncthreads();
    if (tid == 0) {
        __threadfence();
        __hip_atomic_store(&flags[bid], MAGIC1, __ATOMIC_RELEASE, __HIP_MEMORY_SCOPE_AGENT);
    }
    if (tid < NCB)
        while (__hip_atomic_load(&flags[tid], __ATOMIC_ACQUIRE, __HIP_MEMORY_SCOPE_AGENT) != MAGIC1) {}
    __syncthreads();
    __threadfence();

    // ---- phase B: full-stream histogram + threshold T + own-slice compact ----
    const uint4* s4 = (const uint4*)skeys;
    for (int q = tid; q < NTOT / 4; q += 1024) {
        uint4 u = s4[q];
        atomicAdd(&hist[u.x >> 19], 1u);
        atomicAdd(&hist[u.y >> 19], 1u);
        atomicAdd(&hist[u.z >> 19], 1u);
        atomicAdd(&hist[u.w >> 19], 1u);
    }
    __syncthreads();
    unsigned s = 0;
#pragma unroll
    for (int q = 0; q < 8; ++q) s += hist[tid * 8 + q];
    psum[tid] = s;
    __syncthreads();
    if (tid < 256)
        csum[tid] = psum[tid * 4] + psum[tid * 4 + 1] + psum[tid * 4 + 2] + psum[tid * 4 + 3];
    __syncthreads();
    if (tid < 64) {
        int lane = tid;
        unsigned c0 = csum[lane * 4 + 0], c1 = csum[lane * 4 + 1];
        unsigned c2 = csum[lane * 4 + 2], c3 = csum[lane * 4 + 3];
        unsigned ls = c0 + c1 + c2 + c3;
        unsigned v = ls;
#pragma unroll
        for (int o = 1; o < 64; o <<= 1) {
            unsigned t = __shfl_down(v, o, 64);
            if (lane + o < 64) v += t;
        }
        unsigned sufExcl = v - ls;
        unsigned a3 = sufExcl;
        unsigned a2 = a3 + c3;
        unsigned a1 = a2 + c2;
        unsigned a0 = a1 + c1;
        if (a0 < TOPN && a0 + c0 >= TOPN) { sB = lane * 4 + 0; sAbove = a0; }
        if (a1 < TOPN && a1 + c1 >= TOPN) { sB = lane * 4 + 1; sAbove = a1; }
        if (a2 < TOPN && a2 + c2 >= TOPN) { sB = lane * 4 + 2; sAbove = a2; }
        if (a3 < TOPN && a3 + c3 >= TOPN) { sB = lane * 4 + 3; sAbove = a3; }
    }
    __syncthreads();
    if (tid < 32) {
        unsigned B = sB, above = sAbove;
        unsigned h = hist[B * 32 + tid];
        unsigned v = h;
#pragma unroll
        for (int o = 1; o < 32; o <<= 1) {
            unsigned t = __shfl_down(v, o, 64);
            if (tid + o < 32) v += t;
        }
        unsigned sufExcl = v - h;
        unsigned ab = above + sufExcl;
        if (ab < TOPN && ab + h >= TOPN) sT = B * 32 + tid;
    }
    __syncthreads();
    unsigned T = sT;
    int base = bid * (NTOT / NCB);                  // 13824-element slice
    const uint4* s4b = (const uint4*)(skeys + base);
    for (int q = tid; q < (NTOT / NCB) / 4; q += 1024) {
        uint4 u = s4b[q];
        unsigned k4[4] = {u.x, u.y, u.z, u.w};
#pragma unroll
        for (int k = 0; k < 4; ++k) {
            if ((k4[k] >> 19) >= T) {
                unsigned lp = atomicAdd(&sCount, 1u);
                if (lp < SLOT) {
                    int m = base + 4 * q + k;
                    unsigned n = (unsigned)((m % NCELL) * 9 + (m / NCELL));
                    cbuf[(bid << 10) + lp] =
                        ((unsigned long long)k4[k] << 32) | (unsigned long long)(~n);
                }
            }
        }
    }
    __syncthreads();
    unsigned cnt = sCount; if (cnt > SLOT) cnt = SLOT;
    for (int e = cnt + tid; e < SLOT; e += 1024) cbuf[(bid << 10) + e] = 0ULL;  // pad
    if (tid == 0) flags[32 + bid] = cnt;            // plain store, ordered by fence below
    // ---- 16-block barrier #2 ----
    __syncthreads();
    if (tid == 0) {
        __threadfence();
        __hip_atomic_store(&flags[16 + bid], MAGIC2, __ATOMIC_RELEASE, __HIP_MEMORY_SCOPE_AGENT);
    }
    if (tid < NCB)
        while (__hip_atomic_load(&flags[16 + tid], __ATOMIC_ACQUIRE, __HIP_MEMORY_SCOPE_AGENT) != MAGIC2) {}
    __syncthreads();
    __threadfence();

    // ---- phase C: rank by counting + scatter (1024 i per block, 8 thr/i) ----
    if (tid < NCB) scnt[tid] = flags[32 + tid];
    __syncthreads();
    int g = tid >> 3;          // 128 groups
    int slice = tid & 7;
    unsigned long long ki[8];
    unsigned cr[8];
#pragma unroll
    for (int p = 0; p < 8; ++p) {
        ki[p] = cbuf[(bid << 10) + (p << 7) + g];
        cr[p] = 0;
    }
    for (int jt = 0; jt < CAP2 / 512; ++jt) {
        unsigned cb = scnt[jt >> 1];
        if ((jt & 1) ? (cb <= 512u) : (cb == 0u)) continue;   // block-uniform skip
        __syncthreads();
        if (tid < 512) jk[tid] = cbuf[(jt << 9) + tid];
        __syncthreads();
#pragma unroll
        for (int p = 0; p < 8; ++p) {
            unsigned long long kp = ki[p];
            unsigned c2 = 0;
#pragma unroll 8
            for (int j = 0; j < 64; ++j) c2 += (jk[slice + (j << 3)] > kp) ? 1u : 0u;
            cr[p] += c2;
        }
    }
#pragma unroll
    for (int p = 0; p < 8; ++p) {
        unsigned c2 = cr[p];
        c2 += __shfl_down(c2, 4, 8);
        c2 += __shfl_down(c2, 2, 8);
        c2 += __shfl_down(c2, 1, 8);
        if (slice == 0 && ki[p] != 0ULL && c2 < NPADR) {
            unsigned n = ~(unsigned)ki[p];
            unsigned m = (n % 9u) * (unsigned)NCELL + (n / 9u);
            sortedbox[c2] = boxes[m];
        }
    }
}

// ---------------- all-pairs suppression matrix: word-per-thread (R10 form) ----------------
__global__ __launch_bounds__(256) void matrix_kernel(const float4* __restrict__ sortedbox,
                                                     unsigned long long* __restrict__ rowr,
                                                     unsigned long long* __restrict__ diagw,
                                                     unsigned long long* __restrict__ diagT) {
#pragma clang fp contract(off)
    __shared__ float4 jb[256];
    __shared__ float  ja[256];
    int tid = threadIdx.x;
    int lane = tid & 63, wave = tid >> 6;
    int i0 = blockIdx.y << 6;
    int i = i0 + lane;
    int w = (blockIdx.x << 2) + wave;
    int jbase = blockIdx.x << 8;
    unsigned long long word = 0ULL;

    if (jbase + 255 > i0) {                  // tile not entirely below diagonal
        int jg = jbase + tid;
        float4 v = (jg < NPADR) ? sortedbox[jg] : make_float4(0.f, 0.f, 0.f, 0.f);
        jb[tid] = v;
        ja[tid] = (v.z - v.x) * (v.w - v.y);
        __syncthreads();
        if (w < NW && ((w << 6) + 63) > i) {
            float4 bi = sortedbox[i];
            float ai = (bi.z - bi.x) * (bi.w - bi.y);
            int jl0 = wave << 6;
            int jg0 = (w << 6);
#pragma unroll 8
            for (int j = 0; j < 64; ++j) {
                float4 bj = jb[jl0 + j];
                float aj = ja[jl0 + j];
                float iw = fminf(bi.z, bj.z) - fmaxf(bi.x, bj.x);
                float ih = fminf(bi.w, bj.w) - fmaxf(bi.y, bj.y);
                iw = fmaxf(iw, 0.0f);
                ih = fmaxf(ih, 0.0f);
                float inter = iw * ih;
                float denom = fmaxf(ai + aj - inter, 1e-9f);
                bool sup = (jg0 + j > i) && (inter / denom > 0.7f);
                word |= (unsigned long long)sup << j;
            }
        }
    }
    if (w < NW) {
        rowr[(size_t)i * NW + w] = word;
        if ((i >> 9) == (w >> 3))
            diagw[((size_t)w << 9) + (i & 511)] = word;
        if (w == (i >> 6)) {
            unsigned long long col = 0ULL;
#pragma unroll
            for (int jbit = 0; jbit < 64; ++jbit) {
                unsigned long long m = __ballot((word >> jbit) & 1ULL);
                if (lane == jbit) col = m;
            }
            diagT[((size_t)w << 6) + lane] = col;
        }
    }
}

// ---------------- greedy scan: ballot resolve (unchanged from R12) ----------------
__global__ __launch_bounds__(256) void scan_kernel(const unsigned long long* __restrict__ rowr,
                                                   const unsigned long long* __restrict__ diagw,
                                                   const unsigned long long* __restrict__ diagT,
                                                   const float4* __restrict__ sortedbox,
                                                   float* __restrict__ out) {
    __shared__ __align__(16) unsigned long long cblk[CW * 512];
    __shared__ unsigned long long gm[128];
    __shared__ int keptArr[POSTN];
    __shared__ int s_kept, s_done;
    int tid = threadIdx.x;
    int lane = tid & 63, wave = tid >> 6;

    if (tid < 128) gm[tid] = (tid == 93) ? ~((1ULL << 48) - 1) : 0ULL;
    if (tid == 0) { s_kept = 0; s_done = 0; }
    for (int e = tid; e < CW * 512; e += 256) cblk[e] = diagw[e];
    __syncthreads();

    int keptPrev = 0;
    for (int c = 0; c < NCHUNK; ++c) {
        int wbase = c * CW;
        if (tid < 64) {
            unsigned long long dgT[CW];
#pragma unroll
            for (int q = 0; q < CW; ++q)
                dgT[q] = (wbase + q < NW) ? diagT[((size_t)(wbase + q) << 6) + lane] : 0ULL;
            int kept = s_kept;
            int done = 0;
            for (int q = 0; q < CW && wbase + q < NW; ++q) {
                int w = wbase + q;
                unsigned long long live = ~gm[w];
                if (w == NW - 1) live &= (1ULL << 48) - 1;
                unsigned long long kb = 0ULL;
                while (live) {
                    int b = __ffsll((unsigned long long)live) - 1;
                    bool sup = (dgT[q] >> b) & 1ULL;
                    unsigned long long ball = __ballot(sup);
                    if (lane == 0) keptArr[kept] = (w << 6) + b;
                    kept++;
                    kb |= 1ULL << b;
                    live &= ~(ball | (1ULL << b));
                    if (kept == POSTN) { done = 1; break; }
                }
                if (kb && !done && q < CW - 1) {
                    bool act = (lane > q) && (lane < CW);
                    int base = (lane << 9) + (q << 6);
                    unsigned long long acc = 0ULL;
                    unsigned long long t = kb;
                    while (t) {
                        int b0 = __ffsll((unsigned long long)t) - 1; t &= t - 1;
                        int b1 = 0, b2 = 0, b3 = 0, nb = 1;
                        if (t) { b1 = __ffsll((unsigned long long)t) - 1; t &= t - 1; nb = 2; }
                        if (t) { b2 = __ffsll((unsigned long long)t) - 1; t &= t - 1; nb = 3; }
                        if (t) { b3 = __ffsll((unsigned long long)t) - 1; t &= t - 1; nb = 4; }
                        unsigned long long r0 = act ? cblk[base + b0] : 0ULL;
                        unsigned long long r1 = (act && nb > 1) ? cblk[base + b1] : 0ULL;
                        unsigned long long r2 = (act && nb > 2) ? cblk[base + b2] : 0ULL;
                        unsigned long long r3 = (act && nb > 3) ? cblk[base + b3] : 0ULL;
                        acc |= (r0 | r1) | (r2 | r3);
                    }
                    if (act && acc) atomicOr(&gm[wbase + lane], acc);
                }
                if (done) break;
            }
            if (lane == 0) { s_kept = kept; s_done = done; }
        }
        __syncthreads();
        int keptNow = s_kept;
        bool fin = (s_done != 0) || (c == NCHUNK - 1);
        if (!fin) {
            if (wave >= 2) {
                int wb2 = wbase + CW;
                int rb2 = wb2 << 6;
                for (int e = tid - 128; e < CW * 512; e += 128) {
                    int q = e >> 9, r = e & 511;
                    cblk[e] = (wb2 + q < NW && rb2 + r < NPADR)
                        ? diagw[((size_t)(wb2 + q) << 9) + r] : 0ULL;
                }
            } else {
                int hi = (lane < NW - 64);
                unsigned long long a0 = 0ULL, a1 = 0ULL;
                int s = keptPrev + wave;
                for (; s + 6 < keptNow; s += 8) {
                    size_t r0 = (size_t)keptArr[s] * NW;
                    size_t r1 = (size_t)keptArr[s + 2] * NW;
                    size_t r2 = (size_t)keptArr[s + 4] * NW;
                    size_t r3 = (size_t)keptArr[s + 6] * NW;
                    unsigned long long x0 = rowr[r0 + lane];
                    unsigned long long x1 = rowr[r1 + lane];
                    unsigned long long x2 = rowr[r2 + lane];
                    unsigned long long x3 = rowr[r3 + lane];
                    unsigned long long y0 = hi ? rowr[r0 + 64 + lane] : 0ULL;
                    unsigned long long y1 = hi ? rowr[r1 + 64 + lane] : 0ULL;
                    unsigned long long y2 = hi ? rowr[r2 + 64 + lane] : 0ULL;
                    unsigned long long y3 = hi ? rowr[r3 + 64 + lane] : 0ULL;
                    a0 |= x0 | x1 | x2 | x3;
                    a1 |= y0 | y1 | y2 | y3;
                }
                for (; s < keptNow; s += 2) {
                    size_t r0 = (size_t)keptArr[s] * NW;
                    a0 |= rowr[r0 + lane];
                    if (hi) a1 |= rowr[r0 + 64 + lane];
                }
                if (a0) atomicOr(&gm[lane], a0);
                if (a1) atomicOr(&gm[64 + lane], a1);
            }
        }
        keptPrev = keptNow;
        if (fin) break;
        __syncthreads();
    }
    __syncthreads();

    int kept = s_kept;
    for (int k = tid; k < POSTN; k += 256) {
        float4 bb = make_float4(0.f, 0.f, 0.f, 0.f);
        if (k < kept) bb = sortedbox[keptArr[k]];
        out[k * 5 + 0] = 0.0f;
        out[k * 5 + 1] = bb.x;
        out[k * 5 + 2] = bb.y;
        out[k * 5 + 3] = bb.z;
        out[k * 5 + 4] = bb.w;
    }
}

extern "C" void kernel_launch(void* const* d_in, const int* in_sizes, int n_in,
                              void* d_out, int out_size, void* d_ws, size_t ws_size,
                              hipStream_t stream) {
    const float* scores = (const float*)d_in[0];
    const float* deltas = (const float*)d_in[1];
    const float* iminfo = (const float*)d_in[2];
    char* w = (char*)d_ws;
    // workspace (~5.45 MB). rowr ALIASES boxes+skeys (both dead after front).
    float4*   boxes = (float4*)w;                                   // [0, 3538944)
    unsigned* skeys = (unsigned*)(w + 3538944);                     // [3538944, 4423680)
    unsigned long long* rowr = (unsigned long long*)w;              // [0, 4524032) alias
    unsigned* flags = (unsigned*)(w + 4786176);                     // 64 words: b1/b2/cnts
    unsigned long long* cbuf = (unsigned long long*)(w + 4786432);  // [4786432, 4917504)
    float4* sortedbox = (float4*)(w + 4917504);                     // [4917504, 5013760)
    unsigned long long* diagw = (unsigned long long*)(w + 5013760); // [5013760, 5398784)
    unsigned long long* diagT = (unsigned long long*)(w + 5398784); // [5398784, 5446912)
    float* out = (float*)d_out;

    front_kernel<<<NCB, 1024, 0, stream>>>(scores, deltas, iminfo, boxes, skeys,
                                           flags, cbuf, sortedbox);
    matrix_kernel<<<dim3(24, 94), 256, 0, stream>>>(sortedbox, rowr, diagw, diagT);
    scan_kernel<<<1, 256, 0, stream>>>(rowr, diagw, diagT, sortedbox, out);
}

// Round 14
// 182.308 us; speedup vs baseline: 2.4886x; 2.4886x over previous
//
#include <hip/hip_runtime.h>

#define NCELL 24576      // 128*192 feature cells
#define NTOT  221184     // NCELL * 9
#define NBIN13 8192      // 13-bit score-key histogram bins (LDS)
#define TOPN  6000
#define POSTN 300
#define NPADR 6016       // padded candidate count (94 words of 64)
#define NW    94         // suppression-mask words per row
#define CW    8          // words per scan chunk (512 ranks)
#define NCHUNK 12        // ceil(94/8)
#define NCB   16         // compaction blocks
#define SLOT  1024       // cbuf slot per compaction block
#define CAP2  (NCB*SLOT) // 16384 total cbuf slots

// ---------------- decode anchors + scores, build sort keys ----------------
__global__ void decode_kernel(const float* __restrict__ scores,
                              const float* __restrict__ deltas,
                              const float* __restrict__ iminfo,
                              float4* __restrict__ boxes,
                              unsigned* __restrict__ skeys) {
#pragma clang fp contract(off)
    int c = blockIdx.x * blockDim.x + threadIdx.x;
    if (c >= NCELL) return;
    const float AW[9] = {184.f,368.f,736.f,128.f,256.f,512.f, 88.f,176.f,352.f};
    const float AH[9] = { 96.f,192.f,384.f,128.f,256.f,512.f,176.f,352.f,704.f};
    float sx = (float)((c >> 7) << 4);   // (c/128)*16  -- 'ij' meshgrid quirk
    float sy = (float)((c & 127) << 4);  // (c%128)*16
    float imh = iminfo[0], imw = iminfo[1], ims = iminfo[2];
    float xhi = imw - 1.0f, yhi = imh - 1.0f;
    float ms = 16.0f * ims;
    float ctrx = sx + 8.0f, ctry = sy + 8.0f;
    const float* sbase = scores + 9 * NCELL + c;
    const float* dbase = deltas + c;
#pragma unroll
    for (int a = 0; a < 9; ++a) {
        float sc = sbase[a * NCELL];
        float dx = dbase[(4 * a + 0) * NCELL];
        float dy = dbase[(4 * a + 1) * NCELL];
        float dw = dbase[(4 * a + 2) * NCELL];
        float dh = dbase[(4 * a + 3) * NCELL];
        float pcx = dx * AW[a] + ctrx;
        float pcy = dy * AH[a] + ctry;
        float pw = expf(dw) * AW[a];
        float ph = expf(dh) * AH[a];
        float x1 = pcx - 0.5f * pw;
        float y1 = pcy - 0.5f * ph;
        float x2 = pcx + 0.5f * pw;
        float y2 = pcy + 0.5f * ph;
        x1 = fminf(fmaxf(x1, 0.0f), xhi);
        x2 = fminf(fmaxf(x2, 0.0f), xhi);
        y1 = fminf(fmaxf(y1, 0.0f), yhi);
        y2 = fminf(fmaxf(y2, 0.0f), yhi);
        bool valid = ((x2 - x1 + 1.0f) >= ms) && ((y2 - y1 + 1.0f) >= ms);
        unsigned u = __float_as_uint(sc);
        unsigned key = (u & 0x80000000u) ? ~u : (u | 0x80000000u);
        if (!valid) key = 0x007FFFFFu;   // sort key of -inf
        boxes[a * NCELL + c] = make_float4(x1, y1, x2, y2);
        skeys[a * NCELL + c] = key;
    }
}

// ---------------- per-block LDS hist + redundant T + slice compact (16 blocks) ----------------
__global__ __launch_bounds__(1024) void compactT_kernel(const unsigned* __restrict__ skeys,
                                                        unsigned* __restrict__ meta16,
                                                        unsigned long long* __restrict__ cbuf) {
    __shared__ unsigned hist[NBIN13];      // 32 KB
    __shared__ unsigned psum[1024];
    __shared__ unsigned csum[256];
    __shared__ unsigned sB, sAbove, sT, sCount;
    int tid = threadIdx.x, bid = blockIdx.x;
    for (int b = tid; b < NBIN13; b += 1024) hist[b] = 0u;
    if (tid == 0) sCount = 0u;
    __syncthreads();
    // full-stream histogram (every block sees all keys)
    const uint4* s4 = (const uint4*)skeys;
    for (int q = tid; q < NTOT / 4; q += 1024) {
        uint4 u = s4[q];
        atomicAdd(&hist[u.x >> 19], 1u);
        atomicAdd(&hist[u.y >> 19], 1u);
        atomicAdd(&hist[u.z >> 19], 1u);
        atomicAdd(&hist[u.w >> 19], 1u);
    }
    __syncthreads();
    // threshold T: cum(>=T) >= 6000, cum(>T) < 6000  (identical in every block)
    unsigned s = 0;
#pragma unroll
    for (int q = 0; q < 8; ++q) s += hist[tid * 8 + q];
    psum[tid] = s;
    __syncthreads();
    if (tid < 256)
        csum[tid] = psum[tid * 4] + psum[tid * 4 + 1] + psum[tid * 4 + 2] + psum[tid * 4 + 3];
    __syncthreads();
    if (tid < 64) {
        int lane = tid;
        unsigned c0 = csum[lane * 4 + 0], c1 = csum[lane * 4 + 1];
        unsigned c2 = csum[lane * 4 + 2], c3 = csum[lane * 4 + 3];
        unsigned ls = c0 + c1 + c2 + c3;
        unsigned v = ls;
#pragma unroll
        for (int o = 1; o < 64; o <<= 1) {
            unsigned t = __shfl_down(v, o, 64);
            if (lane + o < 64) v += t;
        }
        unsigned sufExcl = v - ls;
        unsigned a3 = sufExcl;
        unsigned a2 = a3 + c3;
        unsigned a1 = a2 + c2;
        unsigned a0 = a1 + c1;
        if (a0 < TOPN && a0 + c0 >= TOPN) { sB = lane * 4 + 0; sAbove = a0; }
        if (a1 < TOPN && a1 + c1 >= TOPN) { sB = lane * 4 + 1; sAbove = a1; }
        if (a2 < TOPN && a2 + c2 >= TOPN) { sB = lane * 4 + 2; sAbove = a2; }
        if (a3 < TOPN && a3 + c3 >= TOPN) { sB = lane * 4 + 3; sAbove = a3; }
    }
    __syncthreads();
    if (tid < 32) {
        unsigned B = sB, above = sAbove;
        unsigned h = hist[B * 32 + tid];
        unsigned v = h;
#pragma unroll
        for (int o = 1; o < 32; o <<= 1) {
            unsigned t = __shfl_down(v, o, 64);
            if (tid + o < 32) v += t;
        }
        unsigned sufExcl = v - h;
        unsigned ab = above + sufExcl;
        if (ab < TOPN && ab + h >= TOPN) sT = B * 32 + tid;
    }
    __syncthreads();
    // compact OWN slice into private slot (LDS-local positions, no global atomics)
    unsigned T = sT;
    int base = bid * (NTOT / NCB);                  // 13824-element slice
    const uint4* s4b = (const uint4*)(skeys + base);
    for (int q = tid; q < (NTOT / NCB) / 4; q += 1024) {
        uint4 u = s4b[q];
        unsigned k4[4] = {u.x, u.y, u.z, u.w};
#pragma unroll
        for (int k = 0; k < 4; ++k) {
            if ((k4[k] >> 19) >= T) {
                unsigned lp = atomicAdd(&sCount, 1u);
                if (lp < SLOT) {
                    int m = base + 4 * q + k;
                    unsigned n = (unsigned)((m % NCELL) * 9 + (m / NCELL));
                    cbuf[(bid << 10) + lp] =
                        ((unsigned long long)k4[k] << 32) | (unsigned long long)(~n);
                }
            }
        }
    }
    __syncthreads();
    unsigned cnt = sCount; if (cnt > SLOT) cnt = SLOT;
    for (int e = cnt + tid; e < SLOT; e += 1024) cbuf[(bid << 10) + e] = 0ULL;  // pad
    if (tid == 0) meta16[bid] = cnt;
}

// ---------------- rank by counting + scatter over slotted cbuf ----------------
__global__ __launch_bounds__(256) void rankscatter_kernel(const unsigned long long* __restrict__ cbuf,
                                                          const unsigned* __restrict__ meta16,
                                                          const float4* __restrict__ boxes,
                                                          float4* __restrict__ sortedbox) {
    __shared__ unsigned long long jk[512];
    __shared__ unsigned scnt[NCB];
    int tid = threadIdx.x;
    if (tid < NCB) scnt[tid] = meta16[tid];
    __syncthreads();
    int i = blockIdx.x * 32 + (tid >> 3);
    int slice = tid & 7;
    unsigned long long ki = cbuf[i];
    unsigned cr = 0;
    for (int jt = 0; jt < CAP2 / 512; ++jt) {
        int b = jt >> 1;
        unsigned cb = scnt[b];
        if ((jt & 1) ? (cb <= 512u) : (cb == 0u)) continue;   // block-uniform skip
        __syncthreads();
        for (int q = tid; q < 512; q += 256) jk[q] = cbuf[(jt << 9) + q];
        __syncthreads();
#pragma unroll 8
        for (int j = 0; j < 64; ++j) cr += (jk[slice + (j << 3)] > ki) ? 1u : 0u;
    }
    cr += __shfl_down(cr, 4, 8);
    cr += __shfl_down(cr, 2, 8);
    cr += __shfl_down(cr, 1, 8);
    if (slice == 0 && ki != 0ULL && cr < NPADR) {
        unsigned n = ~(unsigned)ki;
        unsigned m = (n % 9u) * (unsigned)NCELL + (n / 9u);
        sortedbox[cr] = boxes[m];
    }
}

// ---------------- all-pairs suppression matrix: word-per-thread (R10 form) ----------------
// grid (24, 94): blockIdx.y = 64-row i-tile; blockIdx.x = one 256-col j-tile.
__global__ __launch_bounds__(256) void matrix_kernel(const float4* __restrict__ sortedbox,
                                                     unsigned long long* __restrict__ rowr,
                                                     unsigned long long* __restrict__ diagw,
                                                     unsigned long long* __restrict__ diagT) {
#pragma clang fp contract(off)
    __shared__ float4 jb[256];
    __shared__ float  ja[256];
    int tid = threadIdx.x;
    int lane = tid & 63, wave = tid >> 6;
    int i0 = blockIdx.y << 6;
    int i = i0 + lane;
    int w = (blockIdx.x << 2) + wave;
    int jbase = blockIdx.x << 8;
    unsigned long long word = 0ULL;

    if (jbase + 255 > i0) {                  // tile not entirely below diagonal
        int jg = jbase + tid;
        float4 v = (jg < NPADR) ? sortedbox[jg] : make_float4(0.f, 0.f, 0.f, 0.f);
        jb[tid] = v;
        ja[tid] = (v.z - v.x) * (v.w - v.y);
        __syncthreads();
        if (w < NW && ((w << 6) + 63) > i) { // this word has bits above the diagonal
            float4 bi = sortedbox[i];
            float ai = (bi.z - bi.x) * (bi.w - bi.y);
            int jl0 = wave << 6;
            int jg0 = (w << 6);
#pragma unroll 8
            for (int j = 0; j < 64; ++j) {
                float4 bj = jb[jl0 + j];
                float aj = ja[jl0 + j];
                float iw = fminf(bi.z, bj.z) - fmaxf(bi.x, bj.x);
                float ih = fminf(bi.w, bj.w) - fmaxf(bi.y, bj.y);
                iw = fmaxf(iw, 0.0f);
                ih = fmaxf(ih, 0.0f);
                float inter = iw * ih;
                float denom = fmaxf(ai + aj - inter, 1e-9f);
                bool sup = (jg0 + j > i) && (inter / denom > 0.7f);
                word |= (unsigned long long)sup << j;
            }
        }
    }
    if (w < NW) {
        rowr[(size_t)i * NW + w] = word;
        if ((i >> 9) == (w >> 3))            // chunk-diagonal word -> word-major copy
            diagw[((size_t)w << 9) + (i & 511)] = word;
        if (w == (i >> 6)) {                 // exact diag 64x64 block: emit transpose
            unsigned long long col = 0ULL;
#pragma unroll
            for (int jbit = 0; jbit < 64; ++jbit) {
                unsigned long long m = __ballot((word >> jbit) & 1ULL);
                if (lane == jbit) col = m;
            }
            diagT[((size_t)w << 6) + lane] = col;
        }
    }
}

// ---------------- greedy scan: ballot resolve + 8-deep MLP propagate ----------------
__global__ __launch_bounds__(256) void scan_kernel(const unsigned long long* __restrict__ rowr,
                                                   const unsigned long long* __restrict__ diagw,
                                                   const unsigned long long* __restrict__ diagT,
                                                   const float4* __restrict__ sortedbox,
                                                   float* __restrict__ out) {
    __shared__ __align__(16) unsigned long long cblk[CW * 512];  // 32 KB, word-major
    __shared__ unsigned long long gm[128];
    __shared__ int keptArr[POSTN];
    __shared__ int s_kept, s_done;
    int tid = threadIdx.x;
    int lane = tid & 63, wave = tid >> 6;

    if (tid < 128) gm[tid] = (tid == 93) ? ~((1ULL << 48) - 1) : 0ULL; // ranks>=6000 dead
    if (tid == 0) { s_kept = 0; s_done = 0; }
    for (int e = tid; e < CW * 512; e += 256) cblk[e] = diagw[e];      // stage chunk 0
    __syncthreads();

    int keptPrev = 0;
    for (int c = 0; c < NCHUNK; ++c) {
        int wbase = c * CW;
        if (tid < 64) {
            unsigned long long dgT[CW];
#pragma unroll
            for (int q = 0; q < CW; ++q)
                dgT[q] = (wbase + q < NW) ? diagT[((size_t)(wbase + q) << 6) + lane] : 0ULL;
            int kept = s_kept;
            int done = 0;
            for (int q = 0; q < CW && wbase + q < NW; ++q) {
                int w = wbase + q;
                unsigned long long live = ~gm[w];
                if (w == NW - 1) live &= (1ULL << 48) - 1;
                unsigned long long kb = 0ULL;
                while (live) {
                    int b = __ffsll((unsigned long long)live) - 1;
                    bool sup = (dgT[q] >> b) & 1ULL;
                    unsigned long long ball = __ballot(sup);
                    if (lane == 0) keptArr[kept] = (w << 6) + b;
                    kept++;
                    kb |= 1ULL << b;
                    live &= ~(ball | (1ULL << b));
                    if (kept == POSTN) { done = 1; break; }
                }
                if (kb && !done && q < CW - 1) {
                    bool act = (lane > q) && (lane < CW);
                    int base = (lane << 9) + (q << 6);
                    unsigned long long acc = 0ULL;
                    unsigned long long t = kb;
                    while (t) {
                        int b0 = __ffsll((unsigned long long)t) - 1; t &= t - 1;
                        int b1 = 0, b2 = 0, b3 = 0, nb = 1;
                        if (t) { b1 = __ffsll((unsigned long long)t) - 1; t &= t - 1; nb = 2; }
                        if (t) { b2 = __ffsll((unsigned long long)t) - 1; t &= t - 1; nb = 3; }
                        if (t) { b3 = __ffsll((unsigned long long)t) - 1; t &= t - 1; nb = 4; }
                        unsigned long long r0 = act ? cblk[base + b0] : 0ULL;
                        unsigned long long r1 = (act && nb > 1) ? cblk[base + b1] : 0ULL;
                        unsigned long long r2 = (act && nb > 2) ? cblk[base + b2] : 0ULL;
                        unsigned long long r3 = (act && nb > 3) ? cblk[base + b3] : 0ULL;
                        acc |= (r0 | r1) | (r2 | r3);
                    }
                    if (act && acc) atomicOr(&gm[wbase + lane], acc);
                }
                if (done) break;
            }
            if (lane == 0) { s_kept = kept; s_done = done; }
        }
        __syncthreads();
        int keptNow = s_kept;
        bool fin = (s_done != 0) || (c == NCHUNK - 1);
        if (!fin) {
            if (wave >= 2) {
                // stage next chunk's diag block (waves 2-3)
                int wb2 = wbase + CW;
                int rb2 = wb2 << 6;
                for (int e = tid - 128; e < CW * 512; e += 128) {
                    int q = e >> 9, r = e & 511;
                    cblk[e] = (wb2 + q < NW && rb2 + r < NPADR)
                        ? diagw[((size_t)(wb2 + q) << 9) + r] : 0ULL;
                }
            } else {
                // propagate kept rows into gm (waves 0-1, 8-row batches -> 16 loads in flight)
                int hi = (lane < NW - 64);
                unsigned long long a0 = 0ULL, a1 = 0ULL;
                int s = keptPrev + wave;
                for (; s + 14 < keptNow; s += 16) {
                    size_t r0 = (size_t)keptArr[s]      * NW;
                    size_t r1 = (size_t)keptArr[s + 2]  * NW;
                    size_t r2 = (size_t)keptArr[s + 4]  * NW;
                    size_t r3 = (size_t)keptArr[s + 6]  * NW;
                    size_t r4 = (size_t)keptArr[s + 8]  * NW;
                    size_t r5 = (size_t)keptArr[s + 10] * NW;
                    size_t r6 = (size_t)keptArr[s + 12] * NW;
                    size_t r7 = (size_t)keptArr[s + 14] * NW;
                    unsigned long long x0 = rowr[r0 + lane];
                    unsigned long long x1 = rowr[r1 + lane];
                    unsigned long long x2 = rowr[r2 + lane];
                    unsigned long long x3 = rowr[r3 + lane];
                    unsigned long long x4 = rowr[r4 + lane];
                    unsigned long long x5 = rowr[r5 + lane];
                    unsigned long long x6 = rowr[r6 + lane];
                    unsigned long long x7 = rowr[r7 + lane];
                    unsigned long long y0 = hi ? rowr[r0 + 64 + lane] : 0ULL;
                    unsigned long long y1 = hi ? rowr[r1 + 64 + lane] : 0ULL;
                    unsigned long long y2 = hi ? rowr[r2 + 64 + lane] : 0ULL;
                    unsigned long long y3 = hi ? rowr[r3 + 64 + lane] : 0ULL;
                    unsigned long long y4 = hi ? rowr[r4 + 64 + lane] : 0ULL;
                    unsigned long long y5 = hi ? rowr[r5 + 64 + lane] : 0ULL;
                    unsigned long long y6 = hi ? rowr[r6 + 64 + lane] : 0ULL;
                    unsigned long long y7 = hi ? rowr[r7 + 64 + lane] : 0ULL;
                    a0 |= (x0 | x1) | (x2 | x3) | (x4 | x5) | (x6 | x7);
                    a1 |= (y0 | y1) | (y2 | y3) | (y4 | y5) | (y6 | y7);
                }
                for (; s < keptNow; s += 2) {
                    size_t r0 = (size_t)keptArr[s] * NW;
                    a0 |= rowr[r0 + lane];
                    if (hi) a1 |= rowr[r0 + 64 + lane];
                }
                if (a0) atomicOr(&gm[lane], a0);
                if (a1) atomicOr(&gm[64 + lane], a1);
            }
        }
        keptPrev = keptNow;
        if (fin) break;
        __syncthreads();
    }
    __syncthreads();

    int kept = s_kept;
    for (int k = tid; k < POSTN; k += 256) {
        float4 bb = make_float4(0.f, 0.f, 0.f, 0.f);
        if (k < kept) bb = sortedbox[keptArr[k]];
        out[k * 5 + 0] = 0.0f;
        out[k * 5 + 1] = bb.x;
        out[k * 5 + 2] = bb.y;
        out[k * 5 + 3] = bb.z;
        out[k * 5 + 4] = bb.w;
    }
}

extern "C" void kernel_launch(void* const* d_in, const int* in_sizes, int n_in,
                              void* d_out, int out_size, void* d_ws, size_t ws_size,
                              hipStream_t stream) {
    const float* scores = (const float*)d_in[0];
    const float* deltas = (const float*)d_in[1];
    const float* iminfo = (const float*)d_in[2];
    char* w = (char*)d_ws;
    // workspace (~5.45 MB). rowr ALIASES boxes+skeys (both dead after rankscatter).
    float4*   boxes = (float4*)w;                                   // [0, 3538944)
    unsigned* skeys = (unsigned*)(w + 3538944);                     // [3538944, 4423680)
    unsigned long long* rowr = (unsigned long long*)w;              // [0, 4524032) alias
    unsigned* meta16 = (unsigned*)(w + 4786176);                    // 16 words
    unsigned long long* cbuf = (unsigned long long*)(w + 4786240);  // [4786240, 4917312)
    float4* sortedbox = (float4*)(w + 4917312);                     // [4917312, 5013568)
    unsigned long long* diagw = (unsigned long long*)(w + 5013568); // [5013568, 5398592)
    unsigned long long* diagT = (unsigned long long*)(w + 5398592); // [5398592, 5446720)
    float* out = (float*)d_out;

    decode_kernel<<<NCELL / 256, 256, 0, stream>>>(scores, deltas, iminfo, boxes, skeys);
    compactT_kernel<<<NCB, 1024, 0, stream>>>(skeys, meta16, cbuf);
    rankscatter_kernel<<<CAP2 / 32, 256, 0, stream>>>(cbuf, meta16, boxes, sortedbox);
    matrix_kernel<<<dim3(24, 94), 256, 0, stream>>>(sortedbox, rowr, diagw, diagT);
    scan_kernel<<<1, 256, 0, stream>>>(rowr, diagw, diagT, sortedbox, out);
}